// Round 10
// baseline (287.284 us; speedup 1.0000x reference)
//
#include <hip/hip_runtime.h>
#include <hip/hip_bf16.h>
#include <stdint.h>

typedef unsigned short u16;
typedef unsigned int   u32;

using short8 = __attribute__((ext_vector_type(8))) short;
using f32x4  = __attribute__((ext_vector_type(4))) float;

// ---------- bf16 helpers ----------
__device__ __forceinline__ float b2f(u32 u) {
    union { u32 i; float f; } v;
    v.i = u << 16;
    return v.f;
}
__device__ __forceinline__ u16 f2b(float f) {
    union { float f; u32 i; } v; v.f = f;
    u32 x = v.i;
    x += 0x7fffu + ((x >> 16) & 1u);   // round-to-nearest-even
    return (u16)(x >> 16);
}
// packed f32x2 -> bf16x2 via v_cvt_pk_bf16_f32 (lo in low half)
__device__ __forceinline__ u32 pkbf16(float lo, float hi) {
    __hip_bfloat162 h = __float22bfloat162_rn(float2{lo, hi});
    return *reinterpret_cast<u32*>(&h);
}
__device__ __forceinline__ float fexp2(float x) {
#if __has_builtin(__builtin_amdgcn_exp2f)
    return __builtin_amdgcn_exp2f(x);
#else
    return exp2f(x);
#endif
}
// combine lo16(a)|lo16(b)<<16 and hi16(a)|hi16(b)<<16 via v_perm_b32
__device__ __forceinline__ u32 perm_lo(u32 a, u32 b) {   // [b.b1,b.b0,a.b1,a.b0]
#if __has_builtin(__builtin_amdgcn_perm)
    return __builtin_amdgcn_perm(b, a, 0x05040100u);
#else
    return (a & 0xffffu) | (b << 16);
#endif
}
__device__ __forceinline__ u32 perm_hi(u32 a, u32 b) {   // [b.b3,b.b2,a.b3,a.b2]
#if __has_builtin(__builtin_amdgcn_perm)
    return __builtin_amdgcn_perm(b, a, 0x07060302u);
#else
    return (a >> 16) | (b & 0xffff0000u);
#endif
}

// ---------- async global->LDS, 16B per lane ----------
__device__ __forceinline__ void gll16(const u16* g, u16* l) {
    __builtin_amdgcn_global_load_lds(
        (const __attribute__((address_space(1))) void*)g,
        (__attribute__((address_space(3))) void*)l, 16, 0, 0);
}

// ---------- prep: fused fp32->bf16 cast (x) + both weight transposes ----------
__global__ __launch_bounds__(256)
void prep(const float* __restrict__ x, u16* __restrict__ xb,
          const float* __restrict__ Wa, u16* __restrict__ Wta,
          const float* __restrict__ Wp, u16* __restrict__ Wtp)
{
    __shared__ float t[32][33];
    const int bx = blockIdx.x;
    if (bx < 4096) {
        const int i = (bx * 256 + threadIdx.x) * 8;
        const float4 a = *reinterpret_cast<const float4*>(x + i);
        const float4 b = *reinterpret_cast<const float4*>(x + i + 4);
        *reinterpret_cast<uint4*>(xb + i) = make_uint4(
            pkbf16(a.x, a.y), pkbf16(a.z, a.w), pkbf16(b.x, b.y), pkbf16(b.z, b.w));
        return;
    }
    constexpr int R = 1024;
    const int tb = bx - 4096;
    const int cb = tb & 127;               // col-block 0..127
    const int r0 = (tb >> 7) * 32;         // row-block 0..31 -> rows
    const bool pa = cb < 96;
    const float* W  = pa ? Wa  : Wp;
    u16*         Wt = pa ? Wta : Wtp;
    const int Ncols = pa ? 3072 : 1024;
    const int c0 = (pa ? cb : cb - 96) * 32;
    const int lx = threadIdx.x & 31, ly = threadIdx.x >> 5;   // 32 x 8
#pragma unroll
    for (int i = 0; i < 4; i++) {
        const int r = ly + i * 8;
        t[r][lx] = W[(size_t)(r0 + r) * Ncols + c0 + lx];
    }
    __syncthreads();
#pragma unroll
    for (int i = 0; i < 4; i++) {
        const int c = ly + i * 8;
        Wt[(size_t)(c0 + c) * R + r0 + lx] = f2b(t[lx][c]);
    }
}

// ---------- MFMA GEMM (m97-style 128x128): C[M,N] = A[M,K] @ Bt[N,K]^T + bias[N] ----
template<typename OT>
__global__ __launch_bounds__(256)
void gemm_mfma(const u16* __restrict__ A, const u16* __restrict__ Bt,
               const float* __restrict__ bias, OT* __restrict__ C,
               int M, int N, int K)
{
    __shared__ u16 As[128 * 32];   // [row][k], row stride 32
    __shared__ u16 Bs[128 * 32];   // [col][k]

    const int tid  = threadIdx.x;
    const int w    = tid >> 6;
    const int lane = tid & 63;
    const int quad = lane >> 4;
    const int c16  = lane & 15;
    const int wr   = w >> 1, wc = w & 1;

    const int m0 = blockIdx.y * 128;
    const int n0 = blockIdx.x * 128;

    const int srow = w * 32 + (lane >> 2);
    const int skc  = (lane & 3) * 8;
    const u16* gA = A  + (size_t)(m0 + srow) * K + skc;
    const u16* gB = Bt + (size_t)(n0 + srow) * K + skc;
    u16* lA = As + w * 32 * 32 + lane * 8;
    u16* lB = Bs + w * 32 * 32 + lane * 8;

    f32x4 acc[4][4];
#pragma unroll
    for (int i = 0; i < 4; i++)
#pragma unroll
        for (int j = 0; j < 4; j++) acc[i][j] = (f32x4){0.f, 0.f, 0.f, 0.f};

    for (int k0 = 0; k0 < K; k0 += 32) {
        __syncthreads();
        gll16(gA + k0,                  lA);
        gll16(gA + k0 + 16 * (size_t)K, lA + 16 * 32);
        gll16(gB + k0,                  lB);
        gll16(gB + k0 + 16 * (size_t)K, lB + 16 * 32);
        __syncthreads();

        short8 af[4], bf[4];
#pragma unroll
        for (int i = 0; i < 4; i++)
            af[i] = *reinterpret_cast<const short8*>(&As[(wr * 64 + i * 16 + c16) * 32 + quad * 8]);
#pragma unroll
        for (int j = 0; j < 4; j++)
            bf[j] = *reinterpret_cast<const short8*>(&Bs[(wc * 64 + j * 16 + c16) * 32 + quad * 8]);
#pragma unroll
        for (int i = 0; i < 4; i++)
#pragma unroll
            for (int j = 0; j < 4; j++)
                acc[i][j] = __builtin_amdgcn_mfma_f32_16x16x32_bf16(af[i], bf[j], acc[i][j], 0, 0, 0);
    }

#pragma unroll
    for (int i = 0; i < 4; i++)
#pragma unroll
        for (int j = 0; j < 4; j++) {
            const int colg = n0 + wc * 64 + j * 16 + c16;
            const float bv = bias[colg];
#pragma unroll
            for (int r = 0; r < 4; r++) {
                const int rowg = m0 + wr * 64 + i * 16 + quad * 4 + r;
                const float v = acc[i][j][r] + bv;
                if constexpr (sizeof(OT) == 2)
                    ((u16*)C)[(size_t)rowg * N + colg] = f2b(v);
                else
                    ((float*)C)[(size_t)rowg * N + colg] = v;
            }
        }
}

// ---------- deep-pipelined 256x256 MFMA GEMM (GEMM1), bf16 out ----------
__global__ __launch_bounds__(512, 2)
void gemm_mfma_256(const u16* __restrict__ A, const u16* __restrict__ Bt,
                   const float* __restrict__ bias, u16* __restrict__ C,
                   int M, int N, int K)
{
    __shared__ u16 ring[4 * 16384];   // 4 x (A[256][32] + B[256][32]) u16 = 128 KiB

    const int tid  = threadIdx.x;
    const int w    = tid >> 6;        // 0..7
    const int lane = tid & 63;
    const int quad = lane >> 4;
    const int c16  = lane & 15;
    const int wr   = w >> 2;          // 0..1  (M half)
    const int wc   = w & 3;           // 0..3  (N quarter)

    // T1: XCD-aware bijective block swizzle (grid 12x32 = 384, 384 % 8 == 0)
    const int nwg  = gridDim.x * gridDim.y;
    const int orig = blockIdx.y * gridDim.x + blockIdx.x;
    const int swz  = (orig & 7) * (nwg >> 3) + (orig >> 3);
    const int bx   = swz % gridDim.x;
    const int by   = swz / gridDim.x;
    const int m0   = by * 256, n0 = bx * 256;

    // staging (per lane): row r0s in half, 16B slot (lane&3); pre-swizzled global
    // source k-slot so the linear gll dest + swizzled read agree (rule #21).
    const int r0s = w * 16 + (lane >> 2);            // 0..127
    const int qs  = (lane & 3) ^ ((r0s >> 1) & 3);   // source k-slot
    const u16* gA = A  + (size_t)(m0 + r0s) * K + qs * 8;
    const u16* gB = Bt + (size_t)(n0 + r0s) * K + qs * 8;
    const size_t hstep = (size_t)128 * K;            // half-tile row step in global
    u16* dstB = ring + w * 512 + lane * 8;           // + slot*16384 + mat*8192 + h*4096

    // fragment read offsets (u16 units); physical k-slot = quad ^ ((row>>1)&3),
    // and (row>>1)&3 == (c16>>1)&3 for all frag rows -> constant per thread.
    const int slot = quad ^ ((c16 >> 1) & 3);
    const int aoff = (wr * 128 + c16) * 32 + slot * 8;         // + i*512 per frag
    const int boff = 8192 + (wc * 64 + c16) * 32 + slot * 8;   // + j*512 per frag

    f32x4 acc[8][4];
#pragma unroll
    for (int i = 0; i < 8; i++)
#pragma unroll
        for (int j = 0; j < 4; j++) acc[i][j] = (f32x4){0.f, 0.f, 0.f, 0.f};

    const int nt = K >> 5;   // K/32 K-tiles (K=1024 -> 32; design requires nt>=3)

    // ---- prologue: stage tiles 0..2 into ring slots 0..2 (12 gll calls)
#pragma unroll
    for (int t = 0; t < 3; t++) {
        u16* db = dstB + t * 16384;
        const size_t ko = (size_t)t * 32;
        gll16(gA + ko,         db);            // A half 0
        gll16(gA + ko + hstep, db + 4096);     // A half 1
        gll16(gB + ko,         db + 8192);     // B half 0
        gll16(gB + ko + hstep, db + 12288);    // B half 1
    }

#pragma unroll 1
    for (int t = 0; t < nt; t++) {
        // counted wait: retire tile t's 4 calls; keep t+1/t+2 (8 calls) in flight
        const int remain = nt - 1 - t;
        if (remain >= 2)      asm volatile("s_waitcnt vmcnt(8)" ::: "memory");
        else if (remain == 1) asm volatile("s_waitcnt vmcnt(4)" ::: "memory");
        else                  asm volatile("s_waitcnt vmcnt(0)" ::: "memory");
        asm volatile("s_barrier" ::: "memory");   // publish all waves' DMA for tile t

        const u16* buf = ring + (t & 3) * 16384;
        const bool pf  = (t + 3) < nt;
        u16* db = dstB + ((t + 3) & 3) * 16384;
        const size_t ko = (size_t)(t + 3) * 32;

        short8 bfr[4], afr[4];

        // ---- phase 0: wave-tile rows 0..63 (A frags 0..3 x all B frags)
#pragma unroll
        for (int j = 0; j < 4; j++)
            bfr[j] = *reinterpret_cast<const short8*>(buf + boff + j * 512);
#pragma unroll
        for (int i = 0; i < 4; i++)
            afr[i] = *reinterpret_cast<const short8*>(buf + aoff + i * 512);
        if (pf) { gll16(gA + ko, db); gll16(gA + ko + hstep, db + 4096); }
        asm volatile("s_waitcnt lgkmcnt(0)" ::: "memory");
        __builtin_amdgcn_sched_barrier(0);        // rule #18: pin MFMA below the wait
        __builtin_amdgcn_s_setprio(1);
#pragma unroll
        for (int i = 0; i < 4; i++)
#pragma unroll
            for (int j = 0; j < 4; j++)
                acc[i][j] = __builtin_amdgcn_mfma_f32_16x16x32_bf16(afr[i], bfr[j], acc[i][j], 0, 0, 0);
        __builtin_amdgcn_s_setprio(0);
        asm volatile("s_barrier" ::: "memory");

        // ---- phase 1: wave-tile rows 64..127 (B frags reused from registers)
#pragma unroll
        for (int i = 0; i < 4; i++)
            afr[i] = *reinterpret_cast<const short8*>(buf + aoff + (i + 4) * 512);
        if (pf) { gll16(gB + ko, db + 8192); gll16(gB + ko + hstep, db + 12288); }
        asm volatile("s_waitcnt lgkmcnt(0)" ::: "memory");
        __builtin_amdgcn_sched_barrier(0);
        __builtin_amdgcn_s_setprio(1);
#pragma unroll
        for (int i = 0; i < 4; i++)
#pragma unroll
            for (int j = 0; j < 4; j++)
                acc[i + 4][j] = __builtin_amdgcn_mfma_f32_16x16x32_bf16(afr[i], bfr[j], acc[i + 4][j], 0, 0, 0);
        __builtin_amdgcn_s_setprio(0);
        asm volatile("s_barrier" ::: "memory");
    }

    // ---- epilogue: coalesced stores through LDS (ring is dead here).
    float bv[4];
#pragma unroll
    for (int j = 0; j < 4; j++) bv[j] = bias[n0 + wc * 64 + j * 16 + c16];

    const int erow = wr * 16 + quad * 4;      // + r  -> local row 0..31
    const int ecol = wc * 64 + c16;           // + j*16
#pragma unroll
    for (int i = 0; i < 8; i++) {
#pragma unroll
        for (int j = 0; j < 4; j++)
#pragma unroll
            for (int r = 0; r < 4; r++)
                ring[(erow + r) * 264 + ecol + j * 16] = f2b(acc[i][j][r] + bv[j]);
        __syncthreads();
#pragma unroll
        for (int rr = 0; rr < 2; rr++) {
            const int lr = rr * 16 + (tid >> 5);          // 0..31
            const int cc = (tid & 31) * 8;                // u16 col chunk
            const uint4 vvec = *reinterpret_cast<const uint4*>(&ring[lr * 264 + cc]);
            const int gr = m0 + (lr >> 4) * 128 + i * 16 + (lr & 15);
            *reinterpret_cast<uint4*>(&C[(size_t)gr * N + n0 + cc]) = vvec;
        }
        __syncthreads();
    }
}

// ---------- Flash attention ----------
// Round-10: clean TLP test. 512-thread blocks (8 waves x 16 q-rows) over the
// SAME paired 128-row q-tiles and 512-block grid as round 6 -> 2 blocks/CU
// co-resident but 16 waves/CU (4/SIMD, was 2/SIMD). Round-8's "TLP doesn't
// help" was confounded (unpairing + LPT tail); this changes ONLY waves/CU.
// Single-group tile_pass (round-6 internals: T2 swizzle, T14 reg stage,
// T5 setprio, T13 defer-max, VALU l-sum + deferred reduction). Staging:
// waves 0-3 stage K, waves 4-7 stage V (same byte patterns as round 6).
struct TileState1 {
    f32x4 O[4];
    float m, l;            // l: per-lane partial (this quad's keys, q = c16)
    short8 qf[2];          // k-halves
    int qbase;             // qt*128 + w*16 ; lane q = qbase + c16
};

__device__ __forceinline__ void tile_pass1(
    const u16* __restrict__ Ks, const u16* __restrict__ Vt,
    u16* __restrict__ plrow,           // per-wave Pl base: [16][64] swizzled
    TileState1& ts, int kt0, int quad, int c16)
{
    const int x7 = c16 & 7;

    // ---- S^T = K Q^T
    f32x4 s[4];
    __builtin_amdgcn_s_setprio(1);
#pragma unroll
    for (int sub = 0; sub < 4; sub++) {
        const int row = sub * 16 + c16;
        short8 kf0 = *reinterpret_cast<const short8*>(&Ks[row * 64 + ((0 + quad) ^ x7) * 8]);
        short8 kf1 = *reinterpret_cast<const short8*>(&Ks[row * 64 + ((4 + quad) ^ x7) * 8]);
        f32x4 a = (f32x4){0.f, 0.f, 0.f, 0.f};
        a = __builtin_amdgcn_mfma_f32_16x16x32_bf16(kf0, ts.qf[0], a, 0, 0, 0);
        s[sub] = __builtin_amdgcn_mfma_f32_16x16x32_bf16(kf1, ts.qf[1], a, 0, 0, 0);
    }
    __builtin_amdgcn_s_setprio(0);

    // ---- causal mask (wave-uniform gate)
    if (kt0 + 63 > ts.qbase) {
        const int qg = ts.qbase + c16;
#pragma unroll
        for (int sub = 0; sub < 4; sub++)
#pragma unroll
            for (int r = 0; r < 4; r++)
                if (kt0 + sub * 16 + quad * 4 + r > qg) s[sub][r] = -INFINITY;
    }

    // ---- online max (tree + 2 cross-quad shfl_xor)
    float m0a = fmaxf(fmaxf(s[0][0], s[0][1]), fmaxf(s[0][2], s[0][3]));
    float m1a = fmaxf(fmaxf(s[1][0], s[1][1]), fmaxf(s[1][2], s[1][3]));
    float m2a = fmaxf(fmaxf(s[2][0], s[2][1]), fmaxf(s[2][2], s[2][3]));
    float m3a = fmaxf(fmaxf(s[3][0], s[3][1]), fmaxf(s[3][2], s[3][3]));
    float mloc = fmaxf(fmaxf(m0a, m1a), fmaxf(m2a, m3a));
    mloc = fmaxf(mloc, __shfl_xor(mloc, 16));
    mloc = fmaxf(mloc, __shfl_xor(mloc, 32));

    // T13 defer-max
    if (!__all(mloc <= ts.m + 8.f)) {
        const float mnew = fmaxf(ts.m, mloc);
        const float al   = fexp2(ts.m - mnew);
        ts.m = mnew;
        ts.l *= al;
#pragma unroll
        for (int r = 0; r < 4; r++) {
            const float alr = __shfl(al, quad * 4 + r);
#pragma unroll
            for (int d = 0; d < 4; d++) ts.O[d][r] *= alr;
        }
    }

    // exp2 + packed P write; per-lane l partial (deferred cross-quad reduce)
    float ls = 0.f;
#pragma unroll
    for (int sub = 0; sub < 4; sub++) {
#pragma unroll
        for (int r = 0; r < 4; r++) s[sub][r] = fexp2(s[sub][r] - ts.m);
        ls += (s[sub][0] + s[sub][1]) + (s[sub][2] + s[sub][3]);
        *reinterpret_cast<uint2*>(
            plrow + c16 * 64 + ((sub * 2 + (quad >> 1)) ^ x7) * 8 + (quad & 1) * 4) =
            make_uint2(pkbf16(s[sub][0], s[sub][1]), pkbf16(s[sub][2], s[sub][3]));
    }
    ts.l += ls;

    // A-layout read back (wave-local; compiler orders DS ops)
    short8 pf[2];
#pragma unroll
    for (int c = 0; c < 2; c++)
        pf[c] = *reinterpret_cast<const short8*>(
            plrow + c16 * 64 + ((c * 4 + quad) ^ x7) * 8);

    // ---- O += P V
    __builtin_amdgcn_s_setprio(1);
#pragma unroll
    for (int dsub = 0; dsub < 4; dsub++) {
        const int row = dsub * 16 + c16;
#pragma unroll
        for (int c = 0; c < 2; c++) {
            short8 vf = *reinterpret_cast<const short8*>(&Vt[row * 64 + ((c * 4 + quad) ^ x7) * 8]);
            ts.O[dsub] = __builtin_amdgcn_mfma_f32_16x16x32_bf16(pf[c], vf, ts.O[dsub], 0, 0, 0);
        }
    }
    __builtin_amdgcn_s_setprio(0);
}

__global__ __launch_bounds__(512)
void attn_flash(const u16* __restrict__ qkv, u16* __restrict__ out)
{
    constexpr int T = 2048, C = 1024, C3 = 3072;

    __shared__ u16 Ks[2][64 * 64];    // double-buffered K-tile [key][d], swizzled
    __shared__ u16 Vt[2][64 * 64];    // double-buffered V-tile [d][key], swizzled
    __shared__ u16 Pl[8][16 * 64];    // per-wave P scratch, swizzled

    const int tid  = threadIdx.x;     // 0..511
    const int w    = tid >> 6;        // 0..7
    const int lane = tid & 63;
    const int quad = lane >> 4;
    const int c16  = lane & 15;

    // ---- XCD-locality decode (bijective): all 8 q-pair blocks of one (b,h)
    // share flat%8 -> same XCD L2 holds that (b,h)'s K/V stream.
    const int flat = blockIdx.y * gridDim.x + blockIdx.x;   // gridDim.x = 8
    const int xcd  = flat & 7;
    const int tt   = flat >> 3;
    const int qp   = tt & 7;                  // q-pair index 0..7
    const int bh   = ((tt >> 3) << 3) | xcd;  // 0..63
    const int qtA  = qp;                      // light tile (128-row units)
    const int qtB  = 15 - qp;                 // heavy tile
    const int h    = bh & 15;
    const int b    = bh >> 4;

    // ---- staging coordinates: waves 0-3 stage K, waves 4-7 stage V
    const bool stK = tid < 256;
    const int st   = stK ? tid : tid - 256;          // 0..255
    // K: row kr, slot pair 2kq,2kq+1  (identical to round 6)
    const int kr  = st >> 2, kq = st & 3;
    // V: keys 2vkp,2vkp+1, d vdg..+7  (identical to round 6)
    const int vkp = st & 31, vdg = (st >> 5) * 8;
    const u16* baseK = qkv + (size_t)(b * T + kr) * C3 + C + h * 64 + kq * 16;
    const u16* baseV = qkv + (size_t)(b * T + 2 * vkp) * C3 + 2 * C + h * 64 + vdg;

    // swizzled staging LDS offsets (u16 units)
    const int kx  = kr & 7;
    const int kd0 = kr * 64 + ((2 * kq + 0) ^ kx) * 8;
    const int kd1 = kr * 64 + ((2 * kq + 1) ^ kx) * 8;
    const int vslot = vkp >> 2, vintra = (vkp & 3) * 2;

    u16* plrow = &Pl[w][0];

    // T14 staging registers (K or V tile for the NEXT iteration lives here)
    uint4 ra, rb;

#pragma unroll 1
    for (int phase = 0; phase < 2; ++phase) {
        const int qt = phase ? qtA : qtB;

        TileState1 ts;
        ts.qbase = qt * 128 + w * 16;
        ts.m = -INFINITY;
        ts.l = 0.f;
#pragma unroll
        for (int d = 0; d < 4; d++) ts.O[d] = (f32x4){0.f, 0.f, 0.f, 0.f};
        // Q fragments pre-scaled by (1/sqrt(64)) * log2(e)  [exp2-domain softmax]
        constexpr float QSCALE = 0.125f * 1.44269504089f;
#pragma unroll
        for (int c = 0; c < 2; c++) {
            short8 rq = *reinterpret_cast<const short8*>(
                qkv + (size_t)(b * T + ts.qbase + c16) * C3 + h * 64 + c * 32 + quad * 8);
#pragma unroll
            for (int j = 0; j < 8; j++)
                ts.qf[c][j] = (short)f2b(b2f((u16)rq[j]) * QSCALE);
        }

        const int ktmax = 2 * qt + 1;        // last 64-key tile index
        const int qwmax = ts.qbase + 15;     // this wave's largest q row

        // prologue: load tile 0 into regs (K half or V half), publish into buf 0
        if (stK) {
            const uint4* gp = reinterpret_cast<const uint4*>(baseK);
            ra = gp[0]; rb = gp[1];
        } else {
            ra = *reinterpret_cast<const uint4*>(baseV);
            rb = *reinterpret_cast<const uint4*>(baseV + C3);
        }
        __syncthreads();   // prior phase's reads of buf0 complete
        if (stK) {
            *reinterpret_cast<uint4*>(&Ks[0][kd0]) = ra;
            *reinterpret_cast<uint4*>(&Ks[0][kd1]) = rb;
        } else {
            const u32* aw = reinterpret_cast<const u32*>(&ra);
            const u32* bw = reinterpret_cast<const u32*>(&rb);
#pragma unroll
            for (int i = 0; i < 4; i++) {
                const int d0 = vdg + 2 * i;      // d0&7 == 2i (vdg % 8 == 0)
                *reinterpret_cast<u32*>(&Vt[0][d0 * 64 + (vslot ^ (2 * i)) * 8 + vintra]) =
                    perm_lo(aw[i], bw[i]);
                *reinterpret_cast<u32*>(&Vt[0][(d0 + 1) * 64 + (vslot ^ (2 * i + 1)) * 8 + vintra]) =
                    perm_hi(aw[i], bw[i]);
            }
        }

        for (int kt = 0; kt <= ktmax; kt++) {
            const int cur = kt & 1;
            __syncthreads();   // publish buf[cur]; fence last iter's reads of buf[cur^1]

            // T14: issue NEXT tile's global loads; latency hides under tile_pass
            if (kt < ktmax) {
                const size_t nk0 = (size_t)(kt + 1) * 64;
                if (stK) {
                    const uint4* gp = reinterpret_cast<const uint4*>(baseK + nk0 * C3);
                    ra = gp[0]; rb = gp[1];
                } else {
                    const u16* g0 = baseV + nk0 * C3;
                    ra = *reinterpret_cast<const uint4*>(g0);
                    rb = *reinterpret_cast<const uint4*>(g0 + C3);
                }
            }

            // waves whose 16 q-rows lie entirely below this key tile skip compute
            if (kt * 64 <= qwmax)
                tile_pass1(Ks[cur], Vt[cur], plrow, ts, kt * 64, quad, c16);

            // write staged regs -> other buffer (readers of it fenced by the
            // barrier at the top of THIS iteration)
            if (kt < ktmax) {
                const int nxt = cur ^ 1;
                if (stK) {
                    *reinterpret_cast<uint4*>(&Ks[nxt][kd0]) = ra;
                    *reinterpret_cast<uint4*>(&Ks[nxt][kd1]) = rb;
                } else {
                    const u32* aw = reinterpret_cast<const u32*>(&ra);
                    const u32* bw = reinterpret_cast<const u32*>(&rb);
#pragma unroll
                    for (int i = 0; i < 4; i++) {
                        const int d0 = vdg + 2 * i;
                        *reinterpret_cast<u32*>(&Vt[nxt][d0 * 64 + (vslot ^ (2 * i)) * 8 + vintra]) =
                            perm_lo(aw[i], bw[i]);
                        *reinterpret_cast<u32*>(&Vt[nxt][(d0 + 1) * 64 + (vslot ^ (2 * i + 1)) * 8 + vintra]) =
                            perm_hi(aw[i], bw[i]);
                    }
                }
            }
        }

        // ---- epilogue: deferred cross-quad l reduction, then store
        {
            float lsv = ts.l;
            lsv += __shfl_xor(lsv, 16);
            lsv += __shfl_xor(lsv, 32);
            const float inv = 1.0f / lsv;
#pragma unroll
            for (int r = 0; r < 4; r++) {
                const float invr = __shfl(inv, quad * 4 + r);
                const int qrow = ts.qbase + quad * 4 + r;
#pragma unroll
                for (int dsub = 0; dsub < 4; dsub++)
                    out[(size_t)(b * T + qrow) * C + h * 64 + dsub * 16 + c16] =
                        f2b(ts.O[dsub][r] * invr);
            }
        }
    }
}

// ---------- launcher ----------
extern "C" void kernel_launch(void* const* d_in, const int* in_sizes, int n_in,
                              void* d_out, int out_size, void* d_ws, size_t ws_size,
                              hipStream_t stream)
{
    constexpr int B = 4, T = 2048, C = 1024;
    constexpr int M = B * T;          // 8192
    const float* x      = (const float*)d_in[0];
    const float* W_attn = (const float*)d_in[1];
    const float* b_attn = (const float*)d_in[2];
    const float* W_proj = (const float*)d_in[3];
    const float* b_proj = (const float*)d_in[4];
    float* out = (float*)d_out;

    // workspace layout: qkv | {xb / attn_o aliased} | Wt_attn | Wt_proj
    char* p = (char*)d_ws;
    u16* qkv     = (u16*)p;                 p += (size_t)M * 3 * C * sizeof(u16);
    u16* xb      = (u16*)p;
    u16* attn_o  = (u16*)p;                 p += (size_t)M * C * sizeof(u16);
    u16* Wt_attn = (u16*)p;                 p += (size_t)3 * C * C * sizeof(u16);
    u16* Wt_proj = (u16*)p;

    // fused cast + weight transposes (one launch)
    prep<<<dim3(8192), 256, 0, stream>>>(x, xb, W_attn, Wt_attn, W_proj, Wt_proj);

    // GEMM1: deep-pipelined 256x256 (grid 12x32 = 384 blocks, %8 == 0 for T1)
    gemm_mfma_256<<<dim3(3 * C / 256, M / 256), 512, 0, stream>>>(
        xb, Wt_attn, b_attn, qkv, M, 3 * C, C);

    // attn: 512 blocks (8 q-pairs x 64 bh), 512 threads, 8 waves x 16 q-rows
    attn_flash<<<dim3(8, B * 16), 512, 0, stream>>>(qkv, attn_o);

    // GEMM2: keep 128x128 (256-tile grid would be only 128 blocks -> half GPU idle)
    gemm_mfma<float><<<dim3(C / 128, M / 128), 256, 0, stream>>>(
        attn_o, Wt_proj, b_proj, out, M, C, C);
}

// Round 11
// 260.622 us; speedup vs baseline: 1.1023x; 1.1023x over previous
//
#include <hip/hip_runtime.h>
#include <hip/hip_bf16.h>
#include <stdint.h>

typedef unsigned short u16;
typedef unsigned int   u32;

using short8 = __attribute__((ext_vector_type(8))) short;
using f32x4  = __attribute__((ext_vector_type(4))) float;

// ---------- bf16 helpers ----------
__device__ __forceinline__ float b2f(u32 u) {
    union { u32 i; float f; } v;
    v.i = u << 16;
    return v.f;
}
__device__ __forceinline__ u16 f2b(float f) {
    union { float f; u32 i; } v; v.f = f;
    u32 x = v.i;
    x += 0x7fffu + ((x >> 16) & 1u);   // round-to-nearest-even
    return (u16)(x >> 16);
}
// packed f32x2 -> bf16x2 via v_cvt_pk_bf16_f32 (lo in low half)
__device__ __forceinline__ u32 pkbf16(float lo, float hi) {
    __hip_bfloat162 h = __float22bfloat162_rn(float2{lo, hi});
    return *reinterpret_cast<u32*>(&h);
}
__device__ __forceinline__ float fexp2(float x) {
#if __has_builtin(__builtin_amdgcn_exp2f)
    return __builtin_amdgcn_exp2f(x);
#else
    return exp2f(x);
#endif
}
// combine lo16(a)|lo16(b)<<16 and hi16(a)|hi16(b)<<16 via v_perm_b32
__device__ __forceinline__ u32 perm_lo(u32 a, u32 b) {   // [b.b1,b.b0,a.b1,a.b0]
#if __has_builtin(__builtin_amdgcn_perm)
    return __builtin_amdgcn_perm(b, a, 0x05040100u);
#else
    return (a & 0xffffu) | (b << 16);
#endif
}
__device__ __forceinline__ u32 perm_hi(u32 a, u32 b) {   // [b.b3,b.b2,a.b3,a.b2]
#if __has_builtin(__builtin_amdgcn_perm)
    return __builtin_amdgcn_perm(b, a, 0x07060302u);
#else
    return (a >> 16) | (b & 0xffff0000u);
#endif
}

// ---------- async global->LDS, 16B per lane ----------
__device__ __forceinline__ void gll16(const u16* g, u16* l) {
    __builtin_amdgcn_global_load_lds(
        (const __attribute__((address_space(1))) void*)g,
        (__attribute__((address_space(3))) void*)l, 16, 0, 0);
}

// ---------- prep: fused fp32->bf16 cast (x) + both weight transposes ----------
__global__ __launch_bounds__(256)
void prep(const float* __restrict__ x, u16* __restrict__ xb,
          const float* __restrict__ Wa, u16* __restrict__ Wta,
          const float* __restrict__ Wp, u16* __restrict__ Wtp)
{
    __shared__ float t[32][33];
    const int bx = blockIdx.x;
    if (bx < 4096) {
        const int i = (bx * 256 + threadIdx.x) * 8;
        const float4 a = *reinterpret_cast<const float4*>(x + i);
        const float4 b = *reinterpret_cast<const float4*>(x + i + 4);
        *reinterpret_cast<uint4*>(xb + i) = make_uint4(
            pkbf16(a.x, a.y), pkbf16(a.z, a.w), pkbf16(b.x, b.y), pkbf16(b.z, b.w));
        return;
    }
    constexpr int R = 1024;
    const int tb = bx - 4096;
    const int cb = tb & 127;               // col-block 0..127
    const int r0 = (tb >> 7) * 32;         // row-block 0..31 -> rows
    const bool pa = cb < 96;
    const float* W  = pa ? Wa  : Wp;
    u16*         Wt = pa ? Wta : Wtp;
    const int Ncols = pa ? 3072 : 1024;
    const int c0 = (pa ? cb : cb - 96) * 32;
    const int lx = threadIdx.x & 31, ly = threadIdx.x >> 5;   // 32 x 8
#pragma unroll
    for (int i = 0; i < 4; i++) {
        const int r = ly + i * 8;
        t[r][lx] = W[(size_t)(r0 + r) * Ncols + c0 + lx];
    }
    __syncthreads();
#pragma unroll
    for (int i = 0; i < 4; i++) {
        const int c = ly + i * 8;
        Wt[(size_t)(c0 + c) * R + r0 + lx] = f2b(t[lx][c]);
    }
}

// ---------- deep-pipelined 256x256 MFMA GEMM (GEMM1), bf16 out ----------
__global__ __launch_bounds__(512, 2)
void gemm_mfma_256(const u16* __restrict__ A, const u16* __restrict__ Bt,
                   const float* __restrict__ bias, u16* __restrict__ C,
                   int M, int N, int K)
{
    __shared__ u16 ring[4 * 16384];   // 4 x (A[256][32] + B[256][32]) u16 = 128 KiB

    const int tid  = threadIdx.x;
    const int w    = tid >> 6;        // 0..7
    const int lane = tid & 63;
    const int quad = lane >> 4;
    const int c16  = lane & 15;
    const int wr   = w >> 2;          // 0..1  (M half)
    const int wc   = w & 3;           // 0..3  (N quarter)

    // T1: XCD-aware bijective block swizzle (grid 12x32 = 384, 384 % 8 == 0)
    const int nwg  = gridDim.x * gridDim.y;
    const int orig = blockIdx.y * gridDim.x + blockIdx.x;
    const int swz  = (orig & 7) * (nwg >> 3) + (orig >> 3);
    const int bx   = swz % gridDim.x;
    const int by   = swz / gridDim.x;
    const int m0   = by * 256, n0 = bx * 256;

    // staging (per lane): row r0s in half, 16B slot (lane&3); pre-swizzled global
    // source k-slot so the linear gll dest + swizzled read agree (rule #21).
    const int r0s = w * 16 + (lane >> 2);            // 0..127
    const int qs  = (lane & 3) ^ ((r0s >> 1) & 3);   // source k-slot
    const u16* gA = A  + (size_t)(m0 + r0s) * K + qs * 8;
    const u16* gB = Bt + (size_t)(n0 + r0s) * K + qs * 8;
    const size_t hstep = (size_t)128 * K;            // half-tile row step in global
    u16* dstB = ring + w * 512 + lane * 8;           // + slot*16384 + mat*8192 + h*4096

    // fragment read offsets (u16 units); physical k-slot = quad ^ ((row>>1)&3),
    // and (row>>1)&3 == (c16>>1)&3 for all frag rows -> constant per thread.
    const int slot = quad ^ ((c16 >> 1) & 3);
    const int aoff = (wr * 128 + c16) * 32 + slot * 8;         // + i*512 per frag
    const int boff = 8192 + (wc * 64 + c16) * 32 + slot * 8;   // + j*512 per frag

    f32x4 acc[8][4];
#pragma unroll
    for (int i = 0; i < 8; i++)
#pragma unroll
        for (int j = 0; j < 4; j++) acc[i][j] = (f32x4){0.f, 0.f, 0.f, 0.f};

    const int nt = K >> 5;   // K/32 K-tiles (K=1024 -> 32; design requires nt>=3)

    // ---- prologue: stage tiles 0..2 into ring slots 0..2 (12 gll calls)
#pragma unroll
    for (int t = 0; t < 3; t++) {
        u16* db = dstB + t * 16384;
        const size_t ko = (size_t)t * 32;
        gll16(gA + ko,         db);            // A half 0
        gll16(gA + ko + hstep, db + 4096);     // A half 1
        gll16(gB + ko,         db + 8192);     // B half 0
        gll16(gB + ko + hstep, db + 12288);    // B half 1
    }

#pragma unroll 1
    for (int t = 0; t < nt; t++) {
        // counted wait: retire tile t's 4 calls; keep t+1/t+2 (8 calls) in flight
        const int remain = nt - 1 - t;
        if (remain >= 2)      asm volatile("s_waitcnt vmcnt(8)" ::: "memory");
        else if (remain == 1) asm volatile("s_waitcnt vmcnt(4)" ::: "memory");
        else                  asm volatile("s_waitcnt vmcnt(0)" ::: "memory");
        asm volatile("s_barrier" ::: "memory");   // publish all waves' DMA for tile t

        const u16* buf = ring + (t & 3) * 16384;
        const bool pf  = (t + 3) < nt;
        u16* db = dstB + ((t + 3) & 3) * 16384;
        const size_t ko = (size_t)(t + 3) * 32;

        short8 bfr[4], afr[4];

        // ---- phase 0: wave-tile rows 0..63 (A frags 0..3 x all B frags)
#pragma unroll
        for (int j = 0; j < 4; j++)
            bfr[j] = *reinterpret_cast<const short8*>(buf + boff + j * 512);
#pragma unroll
        for (int i = 0; i < 4; i++)
            afr[i] = *reinterpret_cast<const short8*>(buf + aoff + i * 512);
        if (pf) { gll16(gA + ko, db); gll16(gA + ko + hstep, db + 4096); }
        asm volatile("s_waitcnt lgkmcnt(0)" ::: "memory");
        __builtin_amdgcn_sched_barrier(0);        // rule #18: pin MFMA below the wait
        __builtin_amdgcn_s_setprio(1);
#pragma unroll
        for (int i = 0; i < 4; i++)
#pragma unroll
            for (int j = 0; j < 4; j++)
                acc[i][j] = __builtin_amdgcn_mfma_f32_16x16x32_bf16(afr[i], bfr[j], acc[i][j], 0, 0, 0);
        __builtin_amdgcn_s_setprio(0);
        asm volatile("s_barrier" ::: "memory");

        // ---- phase 1: wave-tile rows 64..127 (B frags reused from registers)
#pragma unroll
        for (int i = 0; i < 4; i++)
            afr[i] = *reinterpret_cast<const short8*>(buf + aoff + (i + 4) * 512);
        if (pf) { gll16(gB + ko, db + 8192); gll16(gB + ko + hstep, db + 12288); }
        asm volatile("s_waitcnt lgkmcnt(0)" ::: "memory");
        __builtin_amdgcn_sched_barrier(0);
        __builtin_amdgcn_s_setprio(1);
#pragma unroll
        for (int i = 0; i < 4; i++)
#pragma unroll
            for (int j = 0; j < 4; j++)
                acc[i + 4][j] = __builtin_amdgcn_mfma_f32_16x16x32_bf16(afr[i], bfr[j], acc[i + 4][j], 0, 0, 0);
        __builtin_amdgcn_s_setprio(0);
        asm volatile("s_barrier" ::: "memory");
    }

    // ---- epilogue: coalesced stores through LDS (ring is dead here).
    float bv[4];
#pragma unroll
    for (int j = 0; j < 4; j++) bv[j] = bias[n0 + wc * 64 + j * 16 + c16];

    const int erow = wr * 16 + quad * 4;      // + r  -> local row 0..31
    const int ecol = wc * 64 + c16;           // + j*16
#pragma unroll
    for (int i = 0; i < 8; i++) {
#pragma unroll
        for (int j = 0; j < 4; j++)
#pragma unroll
            for (int r = 0; r < 4; r++)
                ring[(erow + r) * 264 + ecol + j * 16] = f2b(acc[i][j][r] + bv[j]);
        __syncthreads();
#pragma unroll
        for (int rr = 0; rr < 2; rr++) {
            const int lr = rr * 16 + (tid >> 5);          // 0..31
            const int cc = (tid & 31) * 8;                // u16 col chunk
            const uint4 vvec = *reinterpret_cast<const uint4*>(&ring[lr * 264 + cc]);
            const int gr = m0 + (lr >> 4) * 128 + i * 16 + (lr & 15);
            *reinterpret_cast<uint4*>(&C[(size_t)gr * N + n0 + cc]) = vvec;
        }
        __syncthreads();
    }
}

// ---------- deep-pipelined 256x128 MFMA GEMM (GEMM2), f32 out + bias ----------
// Adapted from gemm_mfma_256: BM=256, BN=128, BK=32, 8 waves as 4M x 2N,
// wave-tile 64x64 (16 MFMA/K-tile, single phase). Grid (N/128, M/256) =
// (8, 32) = 256 blocks = exactly 1 block/CU (96 KiB ring), zero-tail round.
// 3 gll calls/tile -> counted vmcnt(6)/(3)/(0). Same pre-swizzled-source +
// swizzled-read pairing (rule #21); invariant (row>>1)&3 == (c16>>1)&3 holds
// (all row offsets are multiples of 16). Race structure identical to the 256²
// kernel: slot (t+3)&3 == (t-1)&3, whose readers drained via their own
// lgkmcnt(0) before passing the bottom barrier of iter t-1.
__global__ __launch_bounds__(512, 2)
void gemm_mfma_256x128(const u16* __restrict__ A, const u16* __restrict__ Bt,
                       const float* __restrict__ bias, float* __restrict__ C,
                       int M, int N, int K)
{
    __shared__ u16 ring[4 * 12288];   // 4 x (A[256][32] + B[128][32]) u16 = 96 KiB

    const int tid  = threadIdx.x;
    const int w    = tid >> 6;        // 0..7
    const int lane = tid & 63;
    const int quad = lane >> 4;
    const int c16  = lane & 15;
    const int wr   = w >> 1;          // 0..3  (M quarter)
    const int wc   = w & 1;           // 0..1  (N half)

    // T1: XCD-aware bijective block swizzle (grid 8x32 = 256, 256 % 8 == 0)
    const int nwg  = gridDim.x * gridDim.y;
    const int orig = blockIdx.y * gridDim.x + blockIdx.x;
    const int swz  = (orig & 7) * (nwg >> 3) + (orig >> 3);
    const int bx   = swz % gridDim.x;
    const int by   = swz / gridDim.x;
    const int m0   = by * 256, n0 = bx * 128;

    // staging: thread t covers row r0s = t>>2 (0..127) of each 128-row region,
    // 16B slot t&3; pre-swizzled global source k-slot (rule #21).
    const int r0s = tid >> 2;
    const int qs  = (tid & 3) ^ ((r0s >> 1) & 3);
    const u16* gA = A  + (size_t)(m0 + r0s) * K + qs * 8;   // A rows: +hstep for half 1
    const u16* gB = Bt + (size_t)(n0 + r0s) * K + qs * 8;   // B rows 0..127
    const size_t hstep = (size_t)128 * K;
    u16* dstB = ring + tid * 8;       // + slot*12288 + region {0, 4096, 8192}

    // fragment read offsets (u16 units)
    const int slot = quad ^ ((c16 >> 1) & 3);
    const int aoff = (wr * 64 + c16) * 32 + slot * 8;          // + i*512 per frag
    const int boff = 8192 + (wc * 64 + c16) * 32 + slot * 8;   // + j*512 per frag

    f32x4 acc[4][4];
#pragma unroll
    for (int i = 0; i < 4; i++)
#pragma unroll
        for (int j = 0; j < 4; j++) acc[i][j] = (f32x4){0.f, 0.f, 0.f, 0.f};

    const int nt = K >> 5;   // 32 K-tiles (design requires nt>=3)

    // ---- prologue: stage tiles 0..2 into ring slots 0..2 (9 gll calls)
#pragma unroll
    for (int t = 0; t < 3; t++) {
        u16* db = dstB + t * 12288;
        const size_t ko = (size_t)t * 32;
        gll16(gA + ko,         db);            // A rows 0..127
        gll16(gA + ko + hstep, db + 4096);     // A rows 128..255
        gll16(gB + ko,         db + 8192);     // B rows 0..127
    }

#pragma unroll 1
    for (int t = 0; t < nt; t++) {
        // counted wait: retire tile t's 3 calls; keep t+1/t+2 (6 calls) in flight
        const int remain = nt - 1 - t;
        if (remain >= 2)      asm volatile("s_waitcnt vmcnt(6)" ::: "memory");
        else if (remain == 1) asm volatile("s_waitcnt vmcnt(3)" ::: "memory");
        else                  asm volatile("s_waitcnt vmcnt(0)" ::: "memory");
        asm volatile("s_barrier" ::: "memory");   // publish all waves' DMA for tile t

        const u16* buf = ring + (t & 3) * 12288;
        const bool pf  = (t + 3) < nt;
        u16* db = dstB + ((t + 3) & 3) * 12288;
        const size_t ko = (size_t)(t + 3) * 32;

        short8 afr[4], bfr[4];
#pragma unroll
        for (int j = 0; j < 4; j++)
            bfr[j] = *reinterpret_cast<const short8*>(buf + boff + j * 512);
#pragma unroll
        for (int i = 0; i < 4; i++)
            afr[i] = *reinterpret_cast<const short8*>(buf + aoff + i * 512);
        if (pf) {
            gll16(gA + ko,         db);
            gll16(gA + ko + hstep, db + 4096);
            gll16(gB + ko,         db + 8192);
        }
        asm volatile("s_waitcnt lgkmcnt(0)" ::: "memory");
        __builtin_amdgcn_sched_barrier(0);        // rule #18
        __builtin_amdgcn_s_setprio(1);
#pragma unroll
        for (int i = 0; i < 4; i++)
#pragma unroll
            for (int j = 0; j < 4; j++)
                acc[i][j] = __builtin_amdgcn_mfma_f32_16x16x32_bf16(afr[i], bfr[j], acc[i][j], 0, 0, 0);
        __builtin_amdgcn_s_setprio(0);
        asm volatile("s_barrier" ::: "memory");
    }

    // ---- epilogue: bias + f32 store (16-lane 64B segments)
    float bv[4];
#pragma unroll
    for (int j = 0; j < 4; j++) bv[j] = bias[n0 + wc * 64 + j * 16 + c16];
#pragma unroll
    for (int i = 0; i < 4; i++)
#pragma unroll
        for (int j = 0; j < 4; j++) {
            const int colg = n0 + wc * 64 + j * 16 + c16;
#pragma unroll
            for (int r = 0; r < 4; r++) {
                const int rowg = m0 + wr * 64 + i * 16 + quad * 4 + r;
                C[(size_t)rowg * N + colg] = acc[i][j][r] + bv[j];
            }
        }
}

// ---------- Flash attention (round-6 configuration: best measured, 84.7 us) ----
// Paired q-tiles (512 blocks, 4 waves x 32 q-rows in 2 groups, shared Pl),
// T2 XOR swizzle, XCD-locality remap, double-buffered K/V, T14 reg stage,
// T5 setprio, T13 defer-max, VALU l-sum with deferred cross-quad reduction.
struct TileState2 {
    f32x4 O[2][4];
    float m[2], l[2];      // per-lane l partial (this quad's keys, q = c16)
    short8 qf[2][2];       // [g][k-half]
    int qbase;             // qt*128 + w*32 ; lane q for group g = qbase+g*16+c16
};

__device__ __forceinline__ void tile_pass2(
    const u16* __restrict__ Ks, const u16* __restrict__ Vt,
    u16* __restrict__ plrow,           // per-wave Pl base: [16][64] swizzled
    TileState2& ts, int kt0, int quad, int c16)
{
    const int x7 = c16 & 7;

    // ---- S^T = K Q^T for both groups; K fragments loaded ONCE, used twice
    f32x4 s[2][4];
    __builtin_amdgcn_s_setprio(1);
#pragma unroll
    for (int sub = 0; sub < 4; sub++) {
        const int row = sub * 16 + c16;
        short8 kf0 = *reinterpret_cast<const short8*>(&Ks[row * 64 + ((0 + quad) ^ x7) * 8]);
        short8 kf1 = *reinterpret_cast<const short8*>(&Ks[row * 64 + ((4 + quad) ^ x7) * 8]);
        f32x4 a0 = (f32x4){0.f, 0.f, 0.f, 0.f};
        a0 = __builtin_amdgcn_mfma_f32_16x16x32_bf16(kf0, ts.qf[0][0], a0, 0, 0, 0);
        s[0][sub] = __builtin_amdgcn_mfma_f32_16x16x32_bf16(kf1, ts.qf[0][1], a0, 0, 0, 0);
        f32x4 a1 = (f32x4){0.f, 0.f, 0.f, 0.f};
        a1 = __builtin_amdgcn_mfma_f32_16x16x32_bf16(kf0, ts.qf[1][0], a1, 0, 0, 0);
        s[1][sub] = __builtin_amdgcn_mfma_f32_16x16x32_bf16(kf1, ts.qf[1][1], a1, 0, 0, 0);
    }
    __builtin_amdgcn_s_setprio(0);

    // ---- per-group softmax; P write + fragment read share ONE Pl buffer
    short8 pf[2][2];
#pragma unroll
    for (int g = 0; g < 2; g++) {
        const int qg = ts.qbase + g * 16 + c16;
        if (kt0 + 63 > ts.qbase + g * 16) {       // wave-uniform diag check
#pragma unroll
            for (int sub = 0; sub < 4; sub++)
#pragma unroll
                for (int r = 0; r < 4; r++)
                    if (kt0 + sub * 16 + quad * 4 + r > qg) s[g][sub][r] = -INFINITY;
        }

        float m0a = fmaxf(fmaxf(s[g][0][0], s[g][0][1]), fmaxf(s[g][0][2], s[g][0][3]));
        float m1a = fmaxf(fmaxf(s[g][1][0], s[g][1][1]), fmaxf(s[g][1][2], s[g][1][3]));
        float m2a = fmaxf(fmaxf(s[g][2][0], s[g][2][1]), fmaxf(s[g][2][2], s[g][2][3]));
        float m3a = fmaxf(fmaxf(s[g][3][0], s[g][3][1]), fmaxf(s[g][3][2], s[g][3][3]));
        float mloc = fmaxf(fmaxf(m0a, m1a), fmaxf(m2a, m3a));
        mloc = fmaxf(mloc, __shfl_xor(mloc, 16));
        mloc = fmaxf(mloc, __shfl_xor(mloc, 32));

        // T13 defer-max: rescale only when running max grew by > 8 (log2 units)
        if (!__all(mloc <= ts.m[g] + 8.f)) {
            const float mnew = fmaxf(ts.m[g], mloc);
            const float al   = fexp2(ts.m[g] - mnew);
            ts.m[g] = mnew;
            ts.l[g] *= al;
#pragma unroll
            for (int r = 0; r < 4; r++) {
                const float alr = __shfl(al, quad * 4 + r);
#pragma unroll
                for (int d = 0; d < 4; d++) ts.O[g][d][r] *= alr;
            }
        }

        float ls = 0.f;
#pragma unroll
        for (int sub = 0; sub < 4; sub++) {
#pragma unroll
            for (int r = 0; r < 4; r++) s[g][sub][r] = fexp2(s[g][sub][r] - ts.m[g]);
            ls += (s[g][sub][0] + s[g][sub][1]) + (s[g][sub][2] + s[g][sub][3]);
            *reinterpret_cast<uint2*>(
                plrow + c16 * 64 + ((sub * 2 + (quad >> 1)) ^ x7) * 8 + (quad & 1) * 4) =
                make_uint2(pkbf16(s[g][sub][0], s[g][sub][1]), pkbf16(s[g][sub][2], s[g][sub][3]));
        }
        ts.l[g] += ls;

        // A-layout read back for this group (wave-local; must complete before
        // the next group's write -- same addresses, compiler orders DS ops)
#pragma unroll
        for (int c = 0; c < 2; c++)
            pf[g][c] = *reinterpret_cast<const short8*>(
                plrow + c16 * 64 + ((c * 4 + quad) ^ x7) * 8);
    }

    // ---- O += P V; V fragments loaded ONCE, used by both groups
    __builtin_amdgcn_s_setprio(1);
#pragma unroll
    for (int dsub = 0; dsub < 4; dsub++) {
        const int row = dsub * 16 + c16;
#pragma unroll
        for (int c = 0; c < 2; c++) {
            short8 vf = *reinterpret_cast<const short8*>(&Vt[row * 64 + ((c * 4 + quad) ^ x7) * 8]);
            ts.O[0][dsub] = __builtin_amdgcn_mfma_f32_16x16x32_bf16(pf[0][c], vf, ts.O[0][dsub], 0, 0, 0);
            ts.O[1][dsub] = __builtin_amdgcn_mfma_f32_16x16x32_bf16(pf[1][c], vf, ts.O[1][dsub], 0, 0, 0);
        }
    }
    __builtin_amdgcn_s_setprio(0);
}

__global__ __launch_bounds__(256)
void attn_flash(const u16* __restrict__ qkv, u16* __restrict__ out)
{
    constexpr int T = 2048, C = 1024, C3 = 3072;

    __shared__ u16 Ks[2][64 * 64];    // double-buffered K-tile [key][d], swizzled
    __shared__ u16 Vt[2][64 * 64];    // double-buffered V-tile [d][key], swizzled
    __shared__ u16 Pl[4][16 * 64];    // per-wave P scratch (shared by groups), swizzled

    const int tid  = threadIdx.x;
    const int w    = tid >> 6;
    const int lane = tid & 63;
    const int quad = lane >> 4;
    const int c16  = lane & 15;

    // ---- XCD-locality decode (bijective): all 8 q-pair blocks of one (b,h)
    // share flat%8 -> same XCD L2 holds that (b,h)'s K/V stream.
    const int flat = blockIdx.y * gridDim.x + blockIdx.x;   // gridDim.x = 8
    const int xcd  = flat & 7;
    const int tt   = flat >> 3;
    const int qp   = tt & 7;                  // q-pair index 0..7
    const int bh   = ((tt >> 3) << 3) | xcd;  // 0..63
    const int qtA  = qp;                      // light tile (128-row units)
    const int qtB  = 15 - qp;                 // heavy tile
    const int h    = bh & 15;
    const int b    = bh >> 4;

    // staging coordinates
    const int kr  = tid >> 2, kq = tid & 3;          // K: row kr, slot pair 2kq,2kq+1
    const int vkp = tid & 31, vdg = (tid >> 5) * 8;  // V: keys 2vkp,2vkp+1, d vdg..+7
    const u16* baseK = qkv + (size_t)(b * T + kr) * C3 + C + h * 64 + kq * 16;
    const u16* baseV = qkv + (size_t)(b * T + 2 * vkp) * C3 + 2 * C + h * 64 + vdg;

    // swizzled staging LDS offsets (u16 units)
    const int kx  = kr & 7;
    const int kd0 = kr * 64 + ((2 * kq + 0) ^ kx) * 8;
    const int kd1 = kr * 64 + ((2 * kq + 1) ^ kx) * 8;
    const int vslot = vkp >> 2, vintra = (vkp & 3) * 2;

    u16* plrow = &Pl[w][0];

    // T14 staging registers (K/V tile for the NEXT iteration lives here)
    uint4 ka, kb, va, vb;

#pragma unroll 1
    for (int phase = 0; phase < 2; ++phase) {
        const int qt = phase ? qtA : qtB;

        TileState2 ts;
        ts.qbase = qt * 128 + w * 32;
        ts.m[0] = ts.m[1] = -INFINITY;
        ts.l[0] = ts.l[1] = 0.f;
#pragma unroll
        for (int g = 0; g < 2; g++)
#pragma unroll
            for (int d = 0; d < 4; d++) ts.O[g][d] = (f32x4){0.f, 0.f, 0.f, 0.f};
        // Q fragments pre-scaled by (1/sqrt(64)) * log2(e)  [exp2-domain softmax]
        constexpr float QSCALE = 0.125f * 1.44269504089f;
#pragma unroll
        for (int g = 0; g < 2; g++)
#pragma unroll
            for (int c = 0; c < 2; c++) {
                short8 rq = *reinterpret_cast<const short8*>(
                    qkv + (size_t)(b * T + ts.qbase + g * 16 + c16) * C3 + h * 64 + c * 32 + quad * 8);
#pragma unroll
                for (int j = 0; j < 8; j++)
                    ts.qf[g][c][j] = (short)f2b(b2f((u16)rq[j]) * QSCALE);
            }

        const int ktmax = 2 * qt + 1;        // last 64-key tile index
        const int qwmax = ts.qbase + 31;     // this wave's largest q row

        // prologue: load tile 0 into regs, publish into buffer 0
        {
            const uint4* gp = reinterpret_cast<const uint4*>(baseK);
            ka = gp[0]; kb = gp[1];
            va = *reinterpret_cast<const uint4*>(baseV);
            vb = *reinterpret_cast<const uint4*>(baseV + C3);
        }
        __syncthreads();   // prior phase's reads of buf0 complete
        {
            *reinterpret_cast<uint4*>(&Ks[0][kd0]) = ka;
            *reinterpret_cast<uint4*>(&Ks[0][kd1]) = kb;
            const u32* aw = reinterpret_cast<const u32*>(&va);
            const u32* bw = reinterpret_cast<const u32*>(&vb);
#pragma unroll
            for (int i = 0; i < 4; i++) {
                const int d0 = vdg + 2 * i;      // d0&7 == 2i (vdg % 8 == 0)
                *reinterpret_cast<u32*>(&Vt[0][d0 * 64 + (vslot ^ (2 * i)) * 8 + vintra]) =
                    perm_lo(aw[i], bw[i]);
                *reinterpret_cast<u32*>(&Vt[0][(d0 + 1) * 64 + (vslot ^ (2 * i + 1)) * 8 + vintra]) =
                    perm_hi(aw[i], bw[i]);
            }
        }

        for (int kt = 0; kt <= ktmax; kt++) {
            const int cur = kt & 1;
            __syncthreads();   // publish buf[cur]; fence last iter's reads of buf[cur^1]

            // T14: issue NEXT tile's global loads; latency hides under tile_pass
            if (kt < ktmax) {
                const int nk0 = (kt + 1) * 64;
                const uint4* gp = reinterpret_cast<const uint4*>(baseK + (size_t)nk0 * C3);
                ka = gp[0]; kb = gp[1];
                const u16* g0 = baseV + (size_t)nk0 * C3;
                va = *reinterpret_cast<const uint4*>(g0);
                vb = *reinterpret_cast<const uint4*>(g0 + C3);
            }

            // waves whose 32 q-rows lie entirely below this key tile skip compute
            if (kt * 64 <= qwmax)
                tile_pass2(Ks[cur], Vt[cur], plrow, ts, kt * 64, quad, c16);

            // write staged regs -> other buffer (readers of it fenced by the
            // barrier at the top of THIS iteration)
            if (kt < ktmax) {
                const int nxt = cur ^ 1;
                *reinterpret_cast<uint4*>(&Ks[nxt][kd0]) = ka;
                *reinterpret_cast<uint4*>(&Ks[nxt][kd1]) = kb;
                const u32* aw = reinterpret_cast<const u32*>(&va);
                const u32* bw = reinterpret_cast<const u32*>(&vb);
#pragma unroll
                for (int i = 0; i < 4; i++) {
                    const int d0 = vdg + 2 * i;
                    *reinterpret_cast<u32*>(&Vt[nxt][d0 * 64 + (vslot ^ (2 * i)) * 8 + vintra]) =
                        perm_lo(aw[i], bw[i]);
                    *reinterpret_cast<u32*>(&Vt[nxt][(d0 + 1) * 64 + (vslot ^ (2 * i + 1)) * 8 + vintra]) =
                        perm_hi(aw[i], bw[i]);
                }
            }
        }

        // ---- epilogue per group: deferred cross-quad l reduction, then store
#pragma unroll
        for (int g = 0; g < 2; g++) {
            float ls = ts.l[g];
            ls += __shfl_xor(ls, 16);
            ls += __shfl_xor(ls, 32);
            const float inv = 1.0f / ls;
#pragma unroll
            for (int r = 0; r < 4; r++) {
                const float invr = __shfl(inv, quad * 4 + r);
                const int qrow = ts.qbase + g * 16 + quad * 4 + r;
#pragma unroll
                for (int dsub = 0; dsub < 4; dsub++)
                    out[(size_t)(b * T + qrow) * C + h * 64 + dsub * 16 + c16] =
                        f2b(ts.O[g][dsub][r] * invr);
            }
        }
    }
}

// ---------- launcher ----------
extern "C" void kernel_launch(void* const* d_in, const int* in_sizes, int n_in,
                              void* d_out, int out_size, void* d_ws, size_t ws_size,
                              hipStream_t stream)
{
    constexpr int B = 4, T = 2048, C = 1024;
    constexpr int M = B * T;          // 8192
    const float* x      = (const float*)d_in[0];
    const float* W_attn = (const float*)d_in[1];
    const float* b_attn = (const float*)d_in[2];
    const float* W_proj = (const float*)d_in[3];
    const float* b_proj = (const float*)d_in[4];
    float* out = (float*)d_out;

    // workspace layout: qkv | {xb / attn_o aliased} | Wt_attn | Wt_proj
    char* p = (char*)d_ws;
    u16* qkv     = (u16*)p;                 p += (size_t)M * 3 * C * sizeof(u16);
    u16* xb      = (u16*)p;
    u16* attn_o  = (u16*)p;                 p += (size_t)M * C * sizeof(u16);
    u16* Wt_attn = (u16*)p;                 p += (size_t)3 * C * C * sizeof(u16);
    u16* Wt_proj = (u16*)p;

    // fused cast + weight transposes (one launch)
    prep<<<dim3(8192), 256, 0, stream>>>(x, xb, W_attn, Wt_attn, W_proj, Wt_proj);

    // GEMM1: deep-pipelined 256x256 (grid 12x32 = 384 blocks, %8 == 0 for T1)
    gemm_mfma_256<<<dim3(3 * C / 256, M / 256), 512, 0, stream>>>(
        xb, Wt_attn, b_attn, qkv, M, 3 * C, C);

    // attn: 512 blocks (8 q-pairs x 64 bh), round-6 configuration (best: 84.7 us)
    attn_flash<<<dim3(8, B * 16), 256, 0, stream>>>(qkv, attn_o);

    // GEMM2: deep-pipelined 256x128, grid (8, 32) = 256 blocks = 1/CU, zero tail
    gemm_mfma_256x128<<<dim3(C / 128, M / 256), 512, 0, stream>>>(
        attn_o, Wt_proj, b_proj, out, M, C, C);
}

// Round 12
// 256.426 us; speedup vs baseline: 1.1203x; 1.0164x over previous
//
#include <hip/hip_runtime.h>
#include <hip/hip_bf16.h>
#include <stdint.h>

typedef unsigned short u16;
typedef unsigned int   u32;

using short8 = __attribute__((ext_vector_type(8))) short;
using f32x4  = __attribute__((ext_vector_type(4))) float;

// ---------- bf16 helpers ----------
__device__ __forceinline__ float b2f(u32 u) {
    union { u32 i; float f; } v;
    v.i = u << 16;
    return v.f;
}
__device__ __forceinline__ u16 f2b(float f) {
    union { float f; u32 i; } v; v.f = f;
    u32 x = v.i;
    x += 0x7fffu + ((x >> 16) & 1u);   // round-to-nearest-even
    return (u16)(x >> 16);
}
// packed f32x2 -> bf16x2 via v_cvt_pk_bf16_f32 (lo in low half)
__device__ __forceinline__ u32 pkbf16(float lo, float hi) {
    __hip_bfloat162 h = __float22bfloat162_rn(float2{lo, hi});
    return *reinterpret_cast<u32*>(&h);
}
__device__ __forceinline__ float fexp2(float x) {
#if __has_builtin(__builtin_amdgcn_exp2f)
    return __builtin_amdgcn_exp2f(x);
#else
    return exp2f(x);
#endif
}
// combine lo16(a)|lo16(b)<<16 and hi16(a)|hi16(b)<<16 via v_perm_b32
__device__ __forceinline__ u32 perm_lo(u32 a, u32 b) {   // [b.b1,b.b0,a.b1,a.b0]
#if __has_builtin(__builtin_amdgcn_perm)
    return __builtin_amdgcn_perm(b, a, 0x05040100u);
#else
    return (a & 0xffffu) | (b << 16);
#endif
}
__device__ __forceinline__ u32 perm_hi(u32 a, u32 b) {   // [b.b3,b.b2,a.b3,a.b2]
#if __has_builtin(__builtin_amdgcn_perm)
    return __builtin_amdgcn_perm(b, a, 0x07060302u);
#else
    return (a >> 16) | (b & 0xffff0000u);
#endif
}

// ---------- async global->LDS, 16B per lane ----------
__device__ __forceinline__ void gll16(const u16* g, u16* l) {
    __builtin_amdgcn_global_load_lds(
        (const __attribute__((address_space(1))) void*)g,
        (__attribute__((address_space(3))) void*)l, 16, 0, 0);
}

// ---------- prep: fused fp32->bf16 cast (x) + both weight transposes ----------
__global__ __launch_bounds__(256)
void prep(const float* __restrict__ x, u16* __restrict__ xb,
          const float* __restrict__ Wa, u16* __restrict__ Wta,
          const float* __restrict__ Wp, u16* __restrict__ Wtp)
{
    __shared__ float t[32][33];
    const int bx = blockIdx.x;
    if (bx < 4096) {
        const int i = (bx * 256 + threadIdx.x) * 8;
        const float4 a = *reinterpret_cast<const float4*>(x + i);
        const float4 b = *reinterpret_cast<const float4*>(x + i + 4);
        *reinterpret_cast<uint4*>(xb + i) = make_uint4(
            pkbf16(a.x, a.y), pkbf16(a.z, a.w), pkbf16(b.x, b.y), pkbf16(b.z, b.w));
        return;
    }
    constexpr int R = 1024;
    const int tb = bx - 4096;
    const int cb = tb & 127;               // col-block 0..127
    const int r0 = (tb >> 7) * 32;         // row-block 0..31 -> rows
    const bool pa = cb < 96;
    const float* W  = pa ? Wa  : Wp;
    u16*         Wt = pa ? Wta : Wtp;
    const int Ncols = pa ? 3072 : 1024;
    const int c0 = (pa ? cb : cb - 96) * 32;
    const int lx = threadIdx.x & 31, ly = threadIdx.x >> 5;   // 32 x 8
#pragma unroll
    for (int i = 0; i < 4; i++) {
        const int r = ly + i * 8;
        t[r][lx] = W[(size_t)(r0 + r) * Ncols + c0 + lx];
    }
    __syncthreads();
#pragma unroll
    for (int i = 0; i < 4; i++) {
        const int c = ly + i * 8;
        Wt[(size_t)(c0 + c) * R + r0 + lx] = f2b(t[lx][c]);
    }
}

// ---------- deep-pipelined 256x128 MFMA GEMM, templated output ----------
// BM=256, BN=128, BK=32, 8 waves as 4M x 2N, wave-tile 64x64 (16 MFMA/K-tile,
// single phase). 96 KiB ring -> 1 block/CU. Grids chosen as exact multiples of
// 256 blocks (zero-tail rounds): GEMM1 (24,32)=768=3 rounds, GEMM2 (8,32)=256=1.
// 3 gll calls/tile -> counted vmcnt(6)/(3)/(0). Pre-swizzled-source + swizzled
// read (rule #21); invariant (row>>1)&3 == (c16>>1)&3 holds (row offsets are
// multiples of 16). Race structure: slot (t+3)&3 == (t-1)&3, whose readers
// drained via their own lgkmcnt(0) before passing iter t-1's bottom barrier.
template<typename OT>
__global__ __launch_bounds__(512, 2)
void gemm_mfma_256x128(const u16* __restrict__ A, const u16* __restrict__ Bt,
                       const float* __restrict__ bias, OT* __restrict__ C,
                       int M, int N, int K)
{
    __shared__ u16 ring[4 * 12288];   // 4 x (A[256][32] + B[128][32]) u16 = 96 KiB

    const int tid  = threadIdx.x;
    const int w    = tid >> 6;        // 0..7
    const int lane = tid & 63;
    const int quad = lane >> 4;
    const int c16  = lane & 15;
    const int wr   = w >> 1;          // 0..3  (M quarter)
    const int wc   = w & 1;           // 0..1  (N half)

    // T1: XCD-aware bijective block swizzle (grid size % 8 == 0)
    const int nwg  = gridDim.x * gridDim.y;
    const int orig = blockIdx.y * gridDim.x + blockIdx.x;
    const int swz  = (orig & 7) * (nwg >> 3) + (orig >> 3);
    const int bx   = swz % gridDim.x;
    const int by   = swz / gridDim.x;
    const int m0   = by * 256, n0 = bx * 128;

    // staging: thread t covers row r0s = t>>2 (0..127) of each 128-row region,
    // 16B slot t&3; pre-swizzled global source k-slot (rule #21).
    const int r0s = tid >> 2;
    const int qs  = (tid & 3) ^ ((r0s >> 1) & 3);
    const u16* gA = A  + (size_t)(m0 + r0s) * K + qs * 8;   // A rows: +hstep for half 1
    const u16* gB = Bt + (size_t)(n0 + r0s) * K + qs * 8;   // B rows 0..127
    const size_t hstep = (size_t)128 * K;
    u16* dstB = ring + tid * 8;       // + slot*12288 + region {0, 4096, 8192}

    // fragment read offsets (u16 units)
    const int slot = quad ^ ((c16 >> 1) & 3);
    const int aoff = (wr * 64 + c16) * 32 + slot * 8;          // + i*512 per frag
    const int boff = 8192 + (wc * 64 + c16) * 32 + slot * 8;   // + j*512 per frag

    f32x4 acc[4][4];
#pragma unroll
    for (int i = 0; i < 4; i++)
#pragma unroll
        for (int j = 0; j < 4; j++) acc[i][j] = (f32x4){0.f, 0.f, 0.f, 0.f};

    const int nt = K >> 5;   // K/32 K-tiles (design requires nt>=3)

    // ---- prologue: stage tiles 0..2 into ring slots 0..2 (9 gll calls)
#pragma unroll
    for (int t = 0; t < 3; t++) {
        u16* db = dstB + t * 12288;
        const size_t ko = (size_t)t * 32;
        gll16(gA + ko,         db);            // A rows 0..127
        gll16(gA + ko + hstep, db + 4096);     // A rows 128..255
        gll16(gB + ko,         db + 8192);     // B rows 0..127
    }

#pragma unroll 1
    for (int t = 0; t < nt; t++) {
        // counted wait: retire tile t's 3 calls; keep t+1/t+2 (6 calls) in flight
        const int remain = nt - 1 - t;
        if (remain >= 2)      asm volatile("s_waitcnt vmcnt(6)" ::: "memory");
        else if (remain == 1) asm volatile("s_waitcnt vmcnt(3)" ::: "memory");
        else                  asm volatile("s_waitcnt vmcnt(0)" ::: "memory");
        asm volatile("s_barrier" ::: "memory");   // publish all waves' DMA for tile t

        const u16* buf = ring + (t & 3) * 12288;
        const bool pf  = (t + 3) < nt;
        u16* db = dstB + ((t + 3) & 3) * 12288;
        const size_t ko = (size_t)(t + 3) * 32;

        short8 afr[4], bfr[4];
#pragma unroll
        for (int j = 0; j < 4; j++)
            bfr[j] = *reinterpret_cast<const short8*>(buf + boff + j * 512);
#pragma unroll
        for (int i = 0; i < 4; i++)
            afr[i] = *reinterpret_cast<const short8*>(buf + aoff + i * 512);
        if (pf) {
            gll16(gA + ko,         db);
            gll16(gA + ko + hstep, db + 4096);
            gll16(gB + ko,         db + 8192);
        }
        asm volatile("s_waitcnt lgkmcnt(0)" ::: "memory");
        __builtin_amdgcn_sched_barrier(0);        // rule #18
        __builtin_amdgcn_s_setprio(1);
#pragma unroll
        for (int i = 0; i < 4; i++)
#pragma unroll
            for (int j = 0; j < 4; j++)
                acc[i][j] = __builtin_amdgcn_mfma_f32_16x16x32_bf16(afr[i], bfr[j], acc[i][j], 0, 0, 0);
        __builtin_amdgcn_s_setprio(0);
        asm volatile("s_barrier" ::: "memory");
    }

    // ---- epilogue: bias + store (f32 scalar or bf16 scalar; 16-lane segments)
    float bv[4];
#pragma unroll
    for (int j = 0; j < 4; j++) bv[j] = bias[n0 + wc * 64 + j * 16 + c16];
#pragma unroll
    for (int i = 0; i < 4; i++)
#pragma unroll
        for (int j = 0; j < 4; j++) {
            const int colg = n0 + wc * 64 + j * 16 + c16;
#pragma unroll
            for (int r = 0; r < 4; r++) {
                const int rowg = m0 + wr * 64 + i * 16 + quad * 4 + r;
                const float v = acc[i][j][r] + bv[j];
                if constexpr (sizeof(OT) == 2)
                    ((u16*)C)[(size_t)rowg * N + colg] = f2b(v);
                else
                    ((float*)C)[(size_t)rowg * N + colg] = v;
            }
        }
}

// ---------- Flash attention (round-6 configuration: session-best attn) ----
// Paired q-tiles (512 blocks, 4 waves x 32 q-rows in 2 groups, shared Pl),
// T2 XOR swizzle, XCD-locality remap, double-buffered K/V, T14 reg stage,
// T5 setprio, T13 defer-max, VALU l-sum with deferred cross-quad reduction.
struct TileState2 {
    f32x4 O[2][4];
    float m[2], l[2];      // per-lane l partial (this quad's keys, q = c16)
    short8 qf[2][2];       // [g][k-half]
    int qbase;             // qt*128 + w*32 ; lane q for group g = qbase+g*16+c16
};

__device__ __forceinline__ void tile_pass2(
    const u16* __restrict__ Ks, const u16* __restrict__ Vt,
    u16* __restrict__ plrow,           // per-wave Pl base: [16][64] swizzled
    TileState2& ts, int kt0, int quad, int c16)
{
    const int x7 = c16 & 7;

    // ---- S^T = K Q^T for both groups; K fragments loaded ONCE, used twice
    f32x4 s[2][4];
    __builtin_amdgcn_s_setprio(1);
#pragma unroll
    for (int sub = 0; sub < 4; sub++) {
        const int row = sub * 16 + c16;
        short8 kf0 = *reinterpret_cast<const short8*>(&Ks[row * 64 + ((0 + quad) ^ x7) * 8]);
        short8 kf1 = *reinterpret_cast<const short8*>(&Ks[row * 64 + ((4 + quad) ^ x7) * 8]);
        f32x4 a0 = (f32x4){0.f, 0.f, 0.f, 0.f};
        a0 = __builtin_amdgcn_mfma_f32_16x16x32_bf16(kf0, ts.qf[0][0], a0, 0, 0, 0);
        s[0][sub] = __builtin_amdgcn_mfma_f32_16x16x32_bf16(kf1, ts.qf[0][1], a0, 0, 0, 0);
        f32x4 a1 = (f32x4){0.f, 0.f, 0.f, 0.f};
        a1 = __builtin_amdgcn_mfma_f32_16x16x32_bf16(kf0, ts.qf[1][0], a1, 0, 0, 0);
        s[1][sub] = __builtin_amdgcn_mfma_f32_16x16x32_bf16(kf1, ts.qf[1][1], a1, 0, 0, 0);
    }
    __builtin_amdgcn_s_setprio(0);

    // ---- per-group softmax; P write + fragment read share ONE Pl buffer
    short8 pf[2][2];
#pragma unroll
    for (int g = 0; g < 2; g++) {
        const int qg = ts.qbase + g * 16 + c16;
        if (kt0 + 63 > ts.qbase + g * 16) {       // wave-uniform diag check
#pragma unroll
            for (int sub = 0; sub < 4; sub++)
#pragma unroll
                for (int r = 0; r < 4; r++)
                    if (kt0 + sub * 16 + quad * 4 + r > qg) s[g][sub][r] = -INFINITY;
        }

        float m0a = fmaxf(fmaxf(s[g][0][0], s[g][0][1]), fmaxf(s[g][0][2], s[g][0][3]));
        float m1a = fmaxf(fmaxf(s[g][1][0], s[g][1][1]), fmaxf(s[g][1][2], s[g][1][3]));
        float m2a = fmaxf(fmaxf(s[g][2][0], s[g][2][1]), fmaxf(s[g][2][2], s[g][2][3]));
        float m3a = fmaxf(fmaxf(s[g][3][0], s[g][3][1]), fmaxf(s[g][3][2], s[g][3][3]));
        float mloc = fmaxf(fmaxf(m0a, m1a), fmaxf(m2a, m3a));
        mloc = fmaxf(mloc, __shfl_xor(mloc, 16));
        mloc = fmaxf(mloc, __shfl_xor(mloc, 32));

        // T13 defer-max: rescale only when running max grew by > 8 (log2 units)
        if (!__all(mloc <= ts.m[g] + 8.f)) {
            const float mnew = fmaxf(ts.m[g], mloc);
            const float al   = fexp2(ts.m[g] - mnew);
            ts.m[g] = mnew;
            ts.l[g] *= al;
#pragma unroll
            for (int r = 0; r < 4; r++) {
                const float alr = __shfl(al, quad * 4 + r);
#pragma unroll
                for (int d = 0; d < 4; d++) ts.O[g][d][r] *= alr;
            }
        }

        float ls = 0.f;
#pragma unroll
        for (int sub = 0; sub < 4; sub++) {
#pragma unroll
            for (int r = 0; r < 4; r++) s[g][sub][r] = fexp2(s[g][sub][r] - ts.m[g]);
            ls += (s[g][sub][0] + s[g][sub][1]) + (s[g][sub][2] + s[g][sub][3]);
            *reinterpret_cast<uint2*>(
                plrow + c16 * 64 + ((sub * 2 + (quad >> 1)) ^ x7) * 8 + (quad & 1) * 4) =
                make_uint2(pkbf16(s[g][sub][0], s[g][sub][1]), pkbf16(s[g][sub][2], s[g][sub][3]));
        }
        ts.l[g] += ls;

        // A-layout read back for this group (wave-local; must complete before
        // the next group's write -- same addresses, compiler orders DS ops)
#pragma unroll
        for (int c = 0; c < 2; c++)
            pf[g][c] = *reinterpret_cast<const short8*>(
                plrow + c16 * 64 + ((c * 4 + quad) ^ x7) * 8);
    }

    // ---- O += P V; V fragments loaded ONCE, used by both groups
    __builtin_amdgcn_s_setprio(1);
#pragma unroll
    for (int dsub = 0; dsub < 4; dsub++) {
        const int row = dsub * 16 + c16;
#pragma unroll
        for (int c = 0; c < 2; c++) {
            short8 vf = *reinterpret_cast<const short8*>(&Vt[row * 64 + ((c * 4 + quad) ^ x7) * 8]);
            ts.O[0][dsub] = __builtin_amdgcn_mfma_f32_16x16x32_bf16(pf[0][c], vf, ts.O[0][dsub], 0, 0, 0);
            ts.O[1][dsub] = __builtin_amdgcn_mfma_f32_16x16x32_bf16(pf[1][c], vf, ts.O[1][dsub], 0, 0, 0);
        }
    }
    __builtin_amdgcn_s_setprio(0);
}

__global__ __launch_bounds__(256)
void attn_flash(const u16* __restrict__ qkv, u16* __restrict__ out)
{
    constexpr int T = 2048, C = 1024, C3 = 3072;

    __shared__ u16 Ks[2][64 * 64];    // double-buffered K-tile [key][d], swizzled
    __shared__ u16 Vt[2][64 * 64];    // double-buffered V-tile [d][key], swizzled
    __shared__ u16 Pl[4][16 * 64];    // per-wave P scratch (shared by groups), swizzled

    const int tid  = threadIdx.x;
    const int w    = tid >> 6;
    const int lane = tid & 63;
    const int quad = lane >> 4;
    const int c16  = lane & 15;

    // ---- XCD-locality decode (bijective): all 8 q-pair blocks of one (b,h)
    // share flat%8 -> same XCD L2 holds that (b,h)'s K/V stream.
    const int flat = blockIdx.y * gridDim.x + blockIdx.x;   // gridDim.x = 8
    const int xcd  = flat & 7;
    const int tt   = flat >> 3;
    const int qp   = tt & 7;                  // q-pair index 0..7
    const int bh   = ((tt >> 3) << 3) | xcd;  // 0..63
    const int qtA  = qp;                      // light tile (128-row units)
    const int qtB  = 15 - qp;                 // heavy tile
    const int h    = bh & 15;
    const int b    = bh >> 4;

    // staging coordinates
    const int kr  = tid >> 2, kq = tid & 3;          // K: row kr, slot pair 2kq,2kq+1
    const int vkp = tid & 31, vdg = (tid >> 5) * 8;  // V: keys 2vkp,2vkp+1, d vdg..+7
    const u16* baseK = qkv + (size_t)(b * T + kr) * C3 + C + h * 64 + kq * 16;
    const u16* baseV = qkv + (size_t)(b * T + 2 * vkp) * C3 + 2 * C + h * 64 + vdg;

    // swizzled staging LDS offsets (u16 units)
    const int kx  = kr & 7;
    const int kd0 = kr * 64 + ((2 * kq + 0) ^ kx) * 8;
    const int kd1 = kr * 64 + ((2 * kq + 1) ^ kx) * 8;
    const int vslot = vkp >> 2, vintra = (vkp & 3) * 2;

    u16* plrow = &Pl[w][0];

    // T14 staging registers (K/V tile for the NEXT iteration lives here)
    uint4 ka, kb, va, vb;

#pragma unroll 1
    for (int phase = 0; phase < 2; ++phase) {
        const int qt = phase ? qtA : qtB;

        TileState2 ts;
        ts.qbase = qt * 128 + w * 32;
        ts.m[0] = ts.m[1] = -INFINITY;
        ts.l[0] = ts.l[1] = 0.f;
#pragma unroll
        for (int g = 0; g < 2; g++)
#pragma unroll
            for (int d = 0; d < 4; d++) ts.O[g][d] = (f32x4){0.f, 0.f, 0.f, 0.f};
        // Q fragments pre-scaled by (1/sqrt(64)) * log2(e)  [exp2-domain softmax]
        constexpr float QSCALE = 0.125f * 1.44269504089f;
#pragma unroll
        for (int g = 0; g < 2; g++)
#pragma unroll
            for (int c = 0; c < 2; c++) {
                short8 rq = *reinterpret_cast<const short8*>(
                    qkv + (size_t)(b * T + ts.qbase + g * 16 + c16) * C3 + h * 64 + c * 32 + quad * 8);
#pragma unroll
                for (int j = 0; j < 8; j++)
                    ts.qf[g][c][j] = (short)f2b(b2f((u16)rq[j]) * QSCALE);
            }

        const int ktmax = 2 * qt + 1;        // last 64-key tile index
        const int qwmax = ts.qbase + 31;     // this wave's largest q row

        // prologue: load tile 0 into regs, publish into buffer 0
        {
            const uint4* gp = reinterpret_cast<const uint4*>(baseK);
            ka = gp[0]; kb = gp[1];
            va = *reinterpret_cast<const uint4*>(baseV);
            vb = *reinterpret_cast<const uint4*>(baseV + C3);
        }
        __syncthreads();   // prior phase's reads of buf0 complete
        {
            *reinterpret_cast<uint4*>(&Ks[0][kd0]) = ka;
            *reinterpret_cast<uint4*>(&Ks[0][kd1]) = kb;
            const u32* aw = reinterpret_cast<const u32*>(&va);
            const u32* bw = reinterpret_cast<const u32*>(&vb);
#pragma unroll
            for (int i = 0; i < 4; i++) {
                const int d0 = vdg + 2 * i;      // d0&7 == 2i (vdg % 8 == 0)
                *reinterpret_cast<u32*>(&Vt[0][d0 * 64 + (vslot ^ (2 * i)) * 8 + vintra]) =
                    perm_lo(aw[i], bw[i]);
                *reinterpret_cast<u32*>(&Vt[0][(d0 + 1) * 64 + (vslot ^ (2 * i + 1)) * 8 + vintra]) =
                    perm_hi(aw[i], bw[i]);
            }
        }

        for (int kt = 0; kt <= ktmax; kt++) {
            const int cur = kt & 1;
            __syncthreads();   // publish buf[cur]; fence last iter's reads of buf[cur^1]

            // T14: issue NEXT tile's global loads; latency hides under tile_pass
            if (kt < ktmax) {
                const int nk0 = (kt + 1) * 64;
                const uint4* gp = reinterpret_cast<const uint4*>(baseK + (size_t)nk0 * C3);
                ka = gp[0]; kb = gp[1];
                const u16* g0 = baseV + (size_t)nk0 * C3;
                va = *reinterpret_cast<const uint4*>(g0);
                vb = *reinterpret_cast<const uint4*>(g0 + C3);
            }

            // waves whose 32 q-rows lie entirely below this key tile skip compute
            if (kt * 64 <= qwmax)
                tile_pass2(Ks[cur], Vt[cur], plrow, ts, kt * 64, quad, c16);

            // write staged regs -> other buffer (readers of it fenced by the
            // barrier at the top of THIS iteration)
            if (kt < ktmax) {
                const int nxt = cur ^ 1;
                *reinterpret_cast<uint4*>(&Ks[nxt][kd0]) = ka;
                *reinterpret_cast<uint4*>(&Ks[nxt][kd1]) = kb;
                const u32* aw = reinterpret_cast<const u32*>(&va);
                const u32* bw = reinterpret_cast<const u32*>(&vb);
#pragma unroll
                for (int i = 0; i < 4; i++) {
                    const int d0 = vdg + 2 * i;
                    *reinterpret_cast<u32*>(&Vt[nxt][d0 * 64 + (vslot ^ (2 * i)) * 8 + vintra]) =
                        perm_lo(aw[i], bw[i]);
                    *reinterpret_cast<u32*>(&Vt[nxt][(d0 + 1) * 64 + (vslot ^ (2 * i + 1)) * 8 + vintra]) =
                        perm_hi(aw[i], bw[i]);
                }
            }
        }

        // ---- epilogue per group: deferred cross-quad l reduction, then store
#pragma unroll
        for (int g = 0; g < 2; g++) {
            float ls = ts.l[g];
            ls += __shfl_xor(ls, 16);
            ls += __shfl_xor(ls, 32);
            const float inv = 1.0f / ls;
#pragma unroll
            for (int r = 0; r < 4; r++) {
                const float invr = __shfl(inv, quad * 4 + r);
                const int qrow = ts.qbase + g * 16 + quad * 4 + r;
#pragma unroll
                for (int dsub = 0; dsub < 4; dsub++)
                    out[(size_t)(b * T + qrow) * C + h * 64 + dsub * 16 + c16] =
                        f2b(ts.O[g][dsub][r] * invr);
            }
        }
    }
}

// ---------- launcher ----------
extern "C" void kernel_launch(void* const* d_in, const int* in_sizes, int n_in,
                              void* d_out, int out_size, void* d_ws, size_t ws_size,
                              hipStream_t stream)
{
    constexpr int B = 4, T = 2048, C = 1024;
    constexpr int M = B * T;          // 8192
    const float* x      = (const float*)d_in[0];
    const float* W_attn = (const float*)d_in[1];
    const float* b_attn = (const float*)d_in[2];
    const float* W_proj = (const float*)d_in[3];
    const float* b_proj = (const float*)d_in[4];
    float* out = (float*)d_out;

    // workspace layout: qkv | {xb / attn_o aliased} | Wt_attn | Wt_proj
    char* p = (char*)d_ws;
    u16* qkv     = (u16*)p;                 p += (size_t)M * 3 * C * sizeof(u16);
    u16* xb      = (u16*)p;
    u16* attn_o  = (u16*)p;                 p += (size_t)M * C * sizeof(u16);
    u16* Wt_attn = (u16*)p;                 p += (size_t)3 * C * C * sizeof(u16);
    u16* Wt_proj = (u16*)p;

    // fused cast + weight transposes (one launch)
    prep<<<dim3(8192), 256, 0, stream>>>(x, xb, W_attn, Wt_attn, W_proj, Wt_proj);

    // GEMM1: 256x128 tiles, grid (24, 32) = 768 blocks = exactly 3 zero-tail
    // rounds at 1 block/CU (round-11's 256x256 ran 384 blocks = 1.5 rounds,
    // wasting half a round at 50% machine utilization).
    gemm_mfma_256x128<u16><<<dim3(3 * C / 128, M / 256), 512, 0, stream>>>(
        xb, Wt_attn, b_attn, qkv, M, 3 * C, C);

    // attn: 512 blocks (8 q-pairs x 64 bh), round-6 configuration (session best)
    attn_flash<<<dim3(8, B * 16), 256, 0, stream>>>(qkv, attn_o);

    // GEMM2: 256x128, grid (8, 32) = 256 blocks = 1 zero-tail round
    gemm_mfma_256x128<float><<<dim3(C / 128, M / 256), 512, 0, stream>>>(
        attn_o, Wt_proj, b_proj, out, M, C, C);
}